// Round 6
// baseline (1297.060 us; speedup 1.0000x reference)
//
#include <hip/hip_runtime.h>
#include <hip/hip_fp16.h>

// ---------------------------------------------------------------------------
// GCN 2-layer inference on MI355X — round 6: kill random LOADS.
// Empirical law from rounds 1-5: fully-diverged random-line LOADS sustain
// ~0.02-0.035 lines/cyc/CU; random STORES/atomics ~5-10x better.
// => double counting sort (dst-buckets + src-buckets); gather h1 from LDS
//    (src-bucket tile); write per-edge val into dst-sorted order via random
//    16B fire-and-forget stores; aggregation becomes pure streaming.
// F0=512, F1=16 (2 halves of 8), F2=7 (padded 8). Buckets of 64 nodes.
// Packing: payD.x = src | dl<<25 (n<2^25); payS.x = posD | sl<<26 (E<2^26).
// ---------------------------------------------------------------------------

#define F0 512
#define F1 16
#define F2 7
#define BSH 6
#define BSZ 64
#define NB_MAX 1600
#define SRCM 0x1FFFFFF
#define POSM 0x3FFFFFF

// Detect int64 vs int32 edge_index (odd int32 slots all zero => int64 LE).
__global__ void k_detect(const int* __restrict__ ei32, int twoE, int* __restrict__ flag) {
    int t = threadIdx.x;
    int idx = 1 + 2 * t;
    int v = (idx < twoE) ? ei32[idx] : 0;
    unsigned long long b = __ballot(v != 0);
    if (t == 0) *flag = (b == 0ULL) ? 1 : 0;
}

__global__ void k_zero(int* __restrict__ p, int n) {
    int i = blockIdx.x * blockDim.x + threadIdx.x;
    if (i < n) p[i] = 0;
}

// Per-bucket edge counts for key row (0=src, 1=dst).
__global__ __launch_bounds__(256) void k_bcount(
        const int* __restrict__ ei32, const long long* __restrict__ ei64,
        const int* __restrict__ flag, int* __restrict__ bcnt,
        int E, int chunk, int NB, int keyrow) {
    __shared__ int h[NB_MAX];
    int t = threadIdx.x;
    for (int i = t; i < NB; i += 256) h[i] = 0;
    __syncthreads();
    bool f64 = (*flag != 0);
    int e0 = blockIdx.x * chunk;
    int e1 = e0 + chunk; if (e1 > E) e1 = E;
    size_t kb = (size_t)keyrow * E;
    for (int e = e0 + t; e < e1; e += 256) {
        int key = f64 ? (int)ei64[kb + e] : ei32[kb + e];
        atomicAdd(&h[key >> BSH], 1);
    }
    __syncthreads();
    for (int i = t; i < NB; i += 256) {
        int c = h[i];
        if (c) atomicAdd(&bcnt[i], c);
    }
}

// ---- exclusive scan of cnt[NB] -> bbase[NB+1], bcur -----------------------
__global__ __launch_bounds__(256) void k_scanA(const int* __restrict__ cnt,
                                               int* __restrict__ bsum, int n) {
    __shared__ int s[256];
    int t = threadIdx.x, i = blockIdx.x * 256 + t;
    int v = (i < n) ? cnt[i] : 0;
    s[t] = v; __syncthreads();
    for (int off = 128; off > 0; off >>= 1) {
        if (t < off) s[t] += s[t + off];
        __syncthreads();
    }
    if (t == 0) bsum[blockIdx.x] = s[0];
}

__global__ __launch_bounds__(512) void k_scanB(int* __restrict__ bsum, int nb) {
    __shared__ int s[512];
    int t = threadIdx.x;
    int v = (t < nb) ? bsum[t] : 0;
    s[t] = v; __syncthreads();
    for (int off = 1; off < 512; off <<= 1) {
        int tv = (t >= off) ? s[t - off] : 0;
        __syncthreads();
        s[t] += tv;
        __syncthreads();
    }
    if (t < nb) bsum[t] = s[t] - v;  // exclusive
}

__global__ __launch_bounds__(256) void k_scanC(const int* __restrict__ cnt,
                                               const int* __restrict__ bsum,
                                               int* __restrict__ bbase,
                                               int* __restrict__ bcur, int n, int E) {
    __shared__ int s[256];
    int t = threadIdx.x, i = blockIdx.x * 256 + t;
    int v = (i < n) ? cnt[i] : 0;
    s[t] = v; __syncthreads();
    for (int off = 1; off < 256; off <<= 1) {
        int tv = (t >= off) ? s[t - off] : 0;
        __syncthreads();
        s[t] += tv;
        __syncthreads();
    }
    if (i < n) {
        int excl = s[t] - v + bsum[blockIdx.x];
        bbase[i] = excl;
        bcur[i] = excl;
        if (i == n - 1) bbase[n] = E;
    }
}

// Partition by dst-bucket: payD[pos]=(src|dl<<25, w); posD[e]=pos (if given).
__global__ __launch_bounds__(256) void k_bscatterD(
        const int* __restrict__ ei32, const long long* __restrict__ ei64,
        const int* __restrict__ flag, const float* __restrict__ w,
        int* __restrict__ bcur, int2* __restrict__ pay, int* __restrict__ posD,
        int E, int chunk, int NB) {
    __shared__ int h[NB_MAX];
    __shared__ int base[NB_MAX];
    int t = threadIdx.x;
    for (int i = t; i < NB; i += 256) h[i] = 0;
    __syncthreads();
    bool f64 = (*flag != 0);
    int e0 = blockIdx.x * chunk;
    int e1 = e0 + chunk; if (e1 > E) e1 = E;
    for (int e = e0 + t; e < e1; e += 256) {
        int dst = f64 ? (int)ei64[(size_t)E + e] : ei32[(size_t)E + e];
        atomicAdd(&h[dst >> BSH], 1);
    }
    __syncthreads();
    for (int i = t; i < NB; i += 256) {
        int c = h[i];
        if (c) { base[i] = atomicAdd(&bcur[i], c); h[i] = 0; }
    }
    __syncthreads();
    for (int e = e0 + t; e < e1; e += 256) {
        int src, dst;
        if (f64) { src = (int)ei64[e]; dst = (int)ei64[(size_t)E + e]; }
        else     { src = ei32[e];      dst = ei32[(size_t)E + e]; }
        int b = dst >> BSH;
        int rank = atomicAdd(&h[b], 1);
        int pos = base[b] + rank;
        pay[pos] = make_int2(src | ((dst & (BSZ - 1)) << 25), __float_as_int(w[e]));
        if (posD) posD[e] = pos;
    }
}

// Partition by src-bucket: payS[pos]=(posD[e] | sl<<26, w).
__global__ __launch_bounds__(256) void k_bscatterS(
        const int* __restrict__ ei32, const long long* __restrict__ ei64,
        const int* __restrict__ flag, const float* __restrict__ w,
        const int* __restrict__ posD, int* __restrict__ bcur,
        int2* __restrict__ pay, int E, int chunk, int NB) {
    __shared__ int h[NB_MAX];
    __shared__ int base[NB_MAX];
    int t = threadIdx.x;
    for (int i = t; i < NB; i += 256) h[i] = 0;
    __syncthreads();
    bool f64 = (*flag != 0);
    int e0 = blockIdx.x * chunk;
    int e1 = e0 + chunk; if (e1 > E) e1 = E;
    for (int e = e0 + t; e < e1; e += 256) {
        int src = f64 ? (int)ei64[e] : ei32[e];
        atomicAdd(&h[src >> BSH], 1);
    }
    __syncthreads();
    for (int i = t; i < NB; i += 256) {
        int c = h[i];
        if (c) { base[i] = atomicAdd(&bcur[i], c); h[i] = 0; }
    }
    __syncthreads();
    for (int e = e0 + t; e < e1; e += 256) {
        int src = f64 ? (int)ei64[e] : ei32[e];
        int b = src >> BSH;
        int rank = atomicAdd(&h[b], 1);
        unsigned sl = (unsigned)(src & (BSZ - 1));
        pay[base[b] + rank] = make_int2((int)((sl << 26) | (unsigned)posD[e]),
                                        __float_as_int(w[e]));
    }
}

// Degree per dst-bucket from payD, write dinv.
__global__ __launch_bounds__(256) void k_bdeg(
        const int* __restrict__ bbase, const int2* __restrict__ pay,
        float* __restrict__ dinv, int n) {
    __shared__ float dacc[BSZ];
    int b = blockIdx.x, t = threadIdx.x;
    if (t < BSZ) dacc[t] = 1.0f;   // self-loop weight
    __syncthreads();
    int p0 = bbase[b], p1 = bbase[b + 1];
    for (int p = p0 + t; p < p1; p += 256) {
        int2 pr = pay[p];
        atomicAdd(&dacc[((unsigned)pr.x) >> 25], __int_as_float(pr.y));
    }
    __syncthreads();
    if (t < BSZ) {
        int node = (b << BSH) + t;
        if (node < n) {
            float d = dacc[t];
            dinv[node] = (d > 0.f) ? rsqrtf(d) : 0.f;
        }
    }
}

// h1 = x @ W1, fp16 out.
#define PW 516
__global__ __launch_bounds__(256) void k_gemm1(
        const float* __restrict__ x, const float* __restrict__ W1,
        __half* __restrict__ h1h, int n) {
    __shared__ float Wt[F1 * PW];
    int t = threadIdx.x;
    for (int idx = t; idx < F0 * F1; idx += 256) {
        int k = idx >> 4, j = idx & 15;
        Wt[j * PW + k] = W1[idx];
    }
    __syncthreads();
    int r = t >> 4, j = t & 15;
    int row = blockIdx.x * 16 + r;
    if (row >= n) return;
    const float4* xr = (const float4*)(x + (size_t)row * F0);
    const float4* wr = (const float4*)(Wt + j * PW);
    float acc = 0.f;
#pragma unroll 8
    for (int k4 = 0; k4 < F0 / 4; ++k4) {
        float4 xv = xr[k4];
        float4 wv = wr[k4];
        acc += xv.x * wv.x + xv.y * wv.y + xv.z * wv.z + xv.w * wv.w;
    }
    h1h[(size_t)row * F1 + j] = __float2half(acc);
}

// val[posD] = (w*dinv[src]) * H[src][hoff..hoff+8)  — src rows from LDS tile,
// 16B random fire-and-forget store into dst-sorted order.
__global__ __launch_bounds__(256) void k_val(
        const int* __restrict__ bbaseS, const int2* __restrict__ payS,
        const __half* __restrict__ H, int hstride, int hoff,
        const float* __restrict__ dinv, __half* __restrict__ val, int n) {
    __shared__ __align__(16) __half tile[BSZ * 8];
    __shared__ float sdinS[BSZ];
    int b = blockIdx.x, t = threadIdx.x;
    int node0 = b << BSH;
    if (t < BSZ) {
        int node = node0 + t;
        if (node < n) {
            *(int4*)&tile[t * 8] = *(const int4*)&H[(size_t)node * hstride + hoff];
            sdinS[t] = dinv[node];
        } else {
            int4 z = make_int4(0, 0, 0, 0);
            *(int4*)&tile[t * 8] = z;
            sdinS[t] = 0.f;
        }
    }
    __syncthreads();
    int p0 = bbaseS[b], p1 = bbaseS[b + 1];
    for (int p = p0 + t; p < p1; p += 256) {
        int2 q = payS[p];                      // coalesced
        unsigned lo = (unsigned)q.x;
        int posD = lo & POSM;
        int sl = lo >> 26;
        float nm = __int_as_float(q.y) * sdinS[sl];
        const __half2* r = (const __half2*)&tile[sl * 8];
        int4 st;
        __half2* sp = (__half2*)&st;
#pragma unroll
        for (int u = 0; u < 4; ++u) {
            float2 f = __half22float2(r[u]);
            sp[u] = __floats2half2_rn(nm * f.x, nm * f.y);
        }
        *(int4*)&val[(size_t)posD * 8] = st;   // random 16B store, no wait
    }
}

// Layer-1 aggregate (half hsel): pure streaming (payD.x for dl + val 16B),
// rotated LDS accumulate, epilogue = dinv^2*self + b1 + relu into acc1.
__global__ __launch_bounds__(256) void k_bagg1n(
        const int* __restrict__ bbaseD, const int2* __restrict__ payD,
        const __half* __restrict__ val, const __half* __restrict__ h1h,
        const float* __restrict__ dinv, const float* __restrict__ b1,
        float* __restrict__ acc1, int hsel, int n) {
    __shared__ float acc[BSZ * 8];
    __shared__ float sdin[BSZ];
    int b = blockIdx.x, t = threadIdx.x;
    for (int i = t; i < BSZ * 8; i += 256) acc[i] = 0.f;
    if (t < BSZ) {
        int node = (b << BSH) + t;
        sdin[t] = (node < n) ? dinv[node] : 0.f;
    }
    __syncthreads();
    int p0 = bbaseD[b], p1 = bbaseD[b + 1];
    for (int p = p0 + t; p < p1; p += 256) {
        unsigned lo = (unsigned)payD[p].x;     // coalesced (stride-8)
        int dl = lo >> 25;
        int4 vv = *(const int4*)&val[(size_t)p * 8];   // coalesced 16B
        const __half2* hv = (const __half2*)&vv;
        float s = sdin[dl];
        int rb = dl * 8;
#pragma unroll
        for (int u = 0; u < 4; ++u) {
            float2 g = __half22float2(hv[u]);
            atomicAdd(&acc[rb + ((2 * u + dl) & 7)], s * g.x);
            atomicAdd(&acc[rb + ((2 * u + 1 + dl) & 7)], s * g.y);
        }
    }
    __syncthreads();
    for (int i = t; i < BSZ * 8; i += 256) {
        int dl = i >> 3, jj = i & 7;
        int node = (b << BSH) + dl;
        if (node < n) {
            int j = hsel * 8 + jj;
            float di = sdin[dl];
            float self = __half2float(h1h[(size_t)node * F1 + j]);
            float v = di * di * self + b1[j] + acc[dl * 8 + ((jj + dl) & 7)];
            acc1[(size_t)node * F1 + j] = fmaxf(v, 0.f);
        }
    }
}

// h2 = acc1 @ W2, fp16 out (n x 8, 16B rows).
__global__ __launch_bounds__(256) void k_layer2h(
        const float* __restrict__ acc1, const float* __restrict__ W2,
        __half* __restrict__ h2h, int n) {
    __shared__ float sW[F1 * F2];
    int t = threadIdx.x;
    if (t < F1 * F2) sW[t] = W2[t];
    __syncthreads();
    int i = blockIdx.x * 256 + t;
    if (i >= n) return;
    const float4* a4 = (const float4*)(acc1 + (size_t)i * F1);
    float4 v0 = a4[0], v1 = a4[1], v2 = a4[2], v3 = a4[3];
    float g[F1] = {v0.x, v0.y, v0.z, v0.w, v1.x, v1.y, v1.z, v1.w,
                   v2.x, v2.y, v2.z, v2.w, v3.x, v3.y, v3.z, v3.w};
    float h[8];
#pragma unroll
    for (int c = 0; c < F2; ++c) {
        float s = 0.f;
#pragma unroll
        for (int jj = 0; jj < F1; ++jj) s += g[jj] * sW[jj * F2 + c];
        h[c] = s;
    }
    h[7] = 0.f;
    int4 st;
    __half2* sp = (__half2*)&st;
#pragma unroll
    for (int u = 0; u < 4; ++u) sp[u] = __floats2half2_rn(h[2 * u], h[2 * u + 1]);
    *(int4*)&h2h[(size_t)i * 8] = st;
}

// Layer-2 aggregate: streaming val + payD, LDS acc, bias + log_softmax.
__global__ __launch_bounds__(256) void k_bagg2n(
        const int* __restrict__ bbaseD, const int2* __restrict__ payD,
        const __half* __restrict__ val, const __half* __restrict__ h2h,
        const float* __restrict__ dinv, const float* __restrict__ b2,
        float* __restrict__ out, int n) {
    __shared__ float acc[BSZ * 8];
    __shared__ float sdin[BSZ];
    int b = blockIdx.x, t = threadIdx.x;
    for (int i = t; i < BSZ * 8; i += 256) acc[i] = 0.f;
    if (t < BSZ) {
        int node = (b << BSH) + t;
        sdin[t] = (node < n) ? dinv[node] : 0.f;
    }
    __syncthreads();
    int p0 = bbaseD[b], p1 = bbaseD[b + 1];
    for (int p = p0 + t; p < p1; p += 256) {
        unsigned lo = (unsigned)payD[p].x;
        int dl = lo >> 25;
        int4 vv = *(const int4*)&val[(size_t)p * 8];
        const __half2* hv = (const __half2*)&vv;
        float s = sdin[dl];
        int rb = dl * 8;
#pragma unroll
        for (int u = 0; u < 4; ++u) {
            float2 g = __half22float2(hv[u]);
            atomicAdd(&acc[rb + ((2 * u + dl) & 7)], s * g.x);
            atomicAdd(&acc[rb + ((2 * u + 1 + dl) & 7)], s * g.y);
        }
    }
    __syncthreads();
    if (t < BSZ) {
        int node = (b << BSH) + t;
        if (node < n) {
            float di = sdin[t], s2 = di * di;
            float v[F2];
            float m = -1e30f;
#pragma unroll
            for (int cc = 0; cc < F2; ++cc) {
                float self = __half2float(h2h[(size_t)node * 8 + cc]);
                v[cc] = s2 * self + b2[cc] + acc[t * 8 + ((cc + t) & 7)];
                m = fmaxf(m, v[cc]);
            }
            float s = 0.f;
#pragma unroll
            for (int cc = 0; cc < F2; ++cc) s += __expf(v[cc] - m);
            float ls = __logf(s) + m;
#pragma unroll
            for (int cc = 0; cc < F2; ++cc)
                out[(size_t)node * F2 + cc] = v[cc] - ls;
        }
    }
}

// ---------------- round-5 fallback kernels (if ws too small) ---------------
__global__ __launch_bounds__(256) void k_norm(
        int2* __restrict__ pay, const float* __restrict__ dinv, int E) {
    int e = blockIdx.x * 256 + threadIdx.x;
    if (e >= E) return;
    int2 pr = pay[e];
    int src = ((unsigned)pr.x) & SRCM;
    pr.y = __float_as_int(__int_as_float(pr.y) * dinv[src]);
    pay[e] = pr;
}

__global__ __launch_bounds__(256) void k_bagg1o(
        const int* __restrict__ bbase, const int2* __restrict__ pay,
        const __half* __restrict__ h1h, const float* __restrict__ dinv,
        const float* __restrict__ b1, float* __restrict__ acc1, int n) {
    __shared__ float acc[BSZ * F1];
    __shared__ float sdin[BSZ];
    int b = blockIdx.x, t = threadIdx.x;
    for (int i = t; i < BSZ * F1; i += 256) acc[i] = 0.f;
    if (t < BSZ) {
        int node = (b << BSH) + t;
        sdin[t] = (node < n) ? dinv[node] : 0.f;
    }
    __syncthreads();
    int p0 = bbase[b], p1 = bbase[b + 1];
    for (int p = p0 + t; p < p1; p += 256) {
        int2 q = pay[p];
        unsigned lo = (unsigned)q.x;
        int src = lo & SRCM;
        int dl = lo >> 25;
        float nm = __int_as_float(q.y) * sdin[dl];
        const float4* hp = (const float4*)(h1h + (size_t)src * F1);
        float4 a0 = hp[0], a1 = hp[1];
        const __half2* c0 = (const __half2*)&a0;
        const __half2* c1 = (const __half2*)&a1;
        float v[16];
#pragma unroll
        for (int u = 0; u < 4; ++u) {
            float2 f0 = __half22float2(c0[u]);
            float2 f1 = __half22float2(c1[u]);
            v[2 * u] = f0.x;     v[2 * u + 1] = f0.y;
            v[8 + 2 * u] = f1.x; v[8 + 2 * u + 1] = f1.y;
        }
        int rbase = dl * F1;
#pragma unroll
        for (int k = 0; k < F1; ++k)
            atomicAdd(&acc[rbase + ((k + dl) & 15)], nm * v[k]);
    }
    __syncthreads();
    for (int i = t; i < BSZ * F1; i += 256) {
        int dl = i >> 4, jj = i & 15;
        int node = (b << BSH) + dl;
        if (node < n) {
            float di = sdin[dl];
            float self = __half2float(h1h[(size_t)node * F1 + jj]);
            float v = di * di * self + b1[jj] + acc[dl * F1 + ((jj + dl) & 15)];
            acc1[(size_t)node * F1 + jj] = fmaxf(v, 0.f);
        }
    }
}

__global__ __launch_bounds__(256) void k_layer2f(
        const float* __restrict__ acc1, const float* __restrict__ W2,
        float* __restrict__ h2, int n) {
    __shared__ float sW[F1 * F2];
    int t = threadIdx.x;
    if (t < F1 * F2) sW[t] = W2[t];
    __syncthreads();
    int i = blockIdx.x * 256 + t;
    if (i >= n) return;
    const float4* a4 = (const float4*)(acc1 + (size_t)i * F1);
    float4 v0 = a4[0], v1 = a4[1], v2 = a4[2], v3 = a4[3];
    float g[F1] = {v0.x, v0.y, v0.z, v0.w, v1.x, v1.y, v1.z, v1.w,
                   v2.x, v2.y, v2.z, v2.w, v3.x, v3.y, v3.z, v3.w};
    float h[F2];
#pragma unroll
    for (int c = 0; c < F2; ++c) {
        float s = 0.f;
#pragma unroll
        for (int jj = 0; jj < F1; ++jj) s += g[jj] * sW[jj * F2 + c];
        h[c] = s;
    }
    ((float4*)(h2 + (size_t)i * 8))[0] = make_float4(h[0], h[1], h[2], h[3]);
    ((float4*)(h2 + (size_t)i * 8))[1] = make_float4(h[4], h[5], h[6], 0.f);
}

__global__ __launch_bounds__(256) void k_bagg2o(
        const int* __restrict__ bbase, const int2* __restrict__ pay,
        const float* __restrict__ h2, const float* __restrict__ dinv,
        const float* __restrict__ b2, float* __restrict__ out, int n) {
    __shared__ float acc[BSZ * 8];
    __shared__ float sdin[BSZ];
    int b = blockIdx.x, t = threadIdx.x;
    for (int i = t; i < BSZ * 8; i += 256) acc[i] = 0.f;
    if (t < BSZ) {
        int node = (b << BSH) + t;
        sdin[t] = (node < n) ? dinv[node] : 0.f;
    }
    __syncthreads();
    int p0 = bbase[b], p1 = bbase[b + 1];
    for (int p = p0 + t; p < p1; p += 256) {
        int2 q = pay[p];
        unsigned lo = (unsigned)q.x;
        int src = lo & SRCM;
        int dl = lo >> 25;
        float nm = __int_as_float(q.y) * sdin[dl];
        const float4* hp = (const float4*)(h2 + (size_t)src * 8);
        float4 a0 = hp[0], a1 = hp[1];
        float v[8] = {a0.x, a0.y, a0.z, a0.w, a1.x, a1.y, a1.z, a1.w};
        int rbase = dl * 8;
#pragma unroll
        for (int c = 0; c < 8; ++c)
            atomicAdd(&acc[rbase + ((c + dl) & 7)], nm * v[c]);
    }
    __syncthreads();
    if (t < BSZ) {
        int node = (b << BSH) + t;
        if (node < n) {
            float di = sdin[t], s2 = di * di;
            float v[F2];
            float m = -1e30f;
#pragma unroll
            for (int cc = 0; cc < F2; ++cc) {
                v[cc] = s2 * h2[(size_t)node * 8 + cc] + b2[cc]
                      + acc[t * 8 + ((cc + t) & 7)];
                m = fmaxf(m, v[cc]);
            }
            float s = 0.f;
#pragma unroll
            for (int cc = 0; cc < F2; ++cc) s += __expf(v[cc] - m);
            float ls = __logf(s) + m;
#pragma unroll
            for (int cc = 0; cc < F2; ++cc)
                out[(size_t)node * F2 + cc] = v[cc] - ls;
        }
    }
}

extern "C" void kernel_launch(void* const* d_in, const int* in_sizes, int n_in,
                              void* d_out, int out_size, void* d_ws, size_t ws_size,
                              hipStream_t stream) {
    const float* x  = (const float*)d_in[0];
    const int* ei32 = (const int*)d_in[1];
    const long long* ei64 = (const long long*)d_in[1];
    const float* w  = (const float*)d_in[2];
    const float* W1 = (const float*)d_in[3];
    const float* b1 = (const float*)d_in[4];
    const float* W2 = (const float*)d_in[5];
    const float* b2 = (const float*)d_in[6];
    float* out = (float*)d_out;

    const int n = in_sizes[0] / F0;        // 100000
    const int E = in_sizes[2];             // 3200000
    const int NB = (n + BSZ - 1) >> BSH;   // 1563
    const int snb = (NB + 255) / 256;      // 7

    // ---- workspace layout (dword units) ----
    size_t o = 0;
    auto alloc = [&](size_t dw, size_t al) { o = (o + al - 1) & ~(al - 1); size_t r = o; o += dw; return r; };
    float* ws = (float*)d_ws;
    size_t o_dinv  = alloc(n, 4);
    size_t o_h1h   = alloc((size_t)n * 8, 4);     // n*16 halves
    size_t o_acc1  = alloc((size_t)n * 16, 4);
    size_t o_h2f   = alloc((size_t)n * 8, 4);     // fallback fp32 h2
    size_t o_payD  = alloc((size_t)E * 2, 4);
    size_t o_bcntD = alloc(NB, 1);
    size_t o_bbD   = alloc(NB + 1, 1);
    size_t o_bcurD = alloc(NB, 1);
    size_t o_bsumD = alloc(512, 1);
    size_t o_flag  = alloc(1, 1);
    size_t small_need = o * 4;
    size_t o_h2h   = alloc((size_t)n * 4, 4);     // n*8 halves
    size_t o_posD  = alloc(E, 4);
    size_t o_payS  = alloc((size_t)E * 2, 4);
    size_t o_val   = alloc((size_t)E * 4, 4);     // E*8 halves (16B/edge)
    size_t o_bcntS = alloc(NB, 1);
    size_t o_bbS   = alloc(NB + 1, 1);
    size_t o_bcurS = alloc(NB, 1);
    size_t o_bsumS = alloc(512, 1);
    size_t big_need = o * 4;
    (void)small_need;

    float* dinv  = ws + o_dinv;
    __half* h1h  = (__half*)(ws + o_h1h);
    float* acc1  = ws + o_acc1;
    float* h2f   = ws + o_h2f;
    int2* payD   = (int2*)(ws + o_payD);
    int* bcntD   = (int*)(ws + o_bcntD);
    int* bbD     = (int*)(ws + o_bbD);
    int* bcurD   = (int*)(ws + o_bcurD);
    int* bsumD   = (int*)(ws + o_bsumD);
    int* flag    = (int*)(ws + o_flag);
    __half* h2h  = (__half*)(ws + o_h2h);
    int* posD    = (int*)(ws + o_posD);
    int2* payS   = (int2*)(ws + o_payS);
    __half* val  = (__half*)(ws + o_val);
    int* bcntS   = (int*)(ws + o_bcntS);
    int* bbS     = (int*)(ws + o_bbS);
    int* bcurS   = (int*)(ws + o_bcurS);
    int* bsumS   = (int*)(ws + o_bsumS);

    const bool big = (ws_size >= big_need) && (E < (1 << 26)) && (n < (1 << 25));

    const int B = 256;
    const int SGRID = 256;                         // sort grid (write-combining)
    const int schunk = (E + SGRID - 1) / SGRID;    // 12500

    k_detect<<<1, 64, 0, stream>>>(ei32, 2 * E, flag);
    k_zero<<<(NB + B - 1) / B, B, 0, stream>>>(bcntD, NB);
    k_bcount<<<SGRID, B, 0, stream>>>(ei32, ei64, flag, bcntD, E, schunk, NB, 1);
    k_scanA<<<snb, B, 0, stream>>>(bcntD, bsumD, NB);
    k_scanB<<<1, 512, 0, stream>>>(bsumD, snb);
    k_scanC<<<snb, B, 0, stream>>>(bcntD, bsumD, bbD, bcurD, NB, E);
    k_bscatterD<<<SGRID, B, 0, stream>>>(ei32, ei64, flag, w, bcurD, payD,
                                         big ? posD : (int*)nullptr, E, schunk, NB);
    k_bdeg<<<NB, B, 0, stream>>>(bbD, payD, dinv, n);
    k_gemm1<<<(n + 15) / 16, B, 0, stream>>>(x, W1, h1h, n);

    if (big) {
        k_zero<<<(NB + B - 1) / B, B, 0, stream>>>(bcntS, NB);
        k_bcount<<<SGRID, B, 0, stream>>>(ei32, ei64, flag, bcntS, E, schunk, NB, 0);
        k_scanA<<<snb, B, 0, stream>>>(bcntS, bsumS, NB);
        k_scanB<<<1, 512, 0, stream>>>(bsumS, snb);
        k_scanC<<<snb, B, 0, stream>>>(bcntS, bsumS, bbS, bcurS, NB, E);
        k_bscatterS<<<SGRID, B, 0, stream>>>(ei32, ei64, flag, w, posD, bcurS,
                                             payS, E, schunk, NB);
        for (int hsel = 0; hsel < 2; ++hsel) {
            k_val<<<NB, B, 0, stream>>>(bbS, payS, h1h, F1, hsel * 8, dinv, val, n);
            k_bagg1n<<<NB, B, 0, stream>>>(bbD, payD, val, h1h, dinv, b1, acc1, hsel, n);
        }
        k_layer2h<<<(n + B - 1) / B, B, 0, stream>>>(acc1, W2, h2h, n);
        k_val<<<NB, B, 0, stream>>>(bbS, payS, h2h, 8, 0, dinv, val, n);
        k_bagg2n<<<NB, B, 0, stream>>>(bbD, payD, val, h2h, dinv, b2, out, n);
    } else {
        // round-5 fallback
        k_norm<<<(E + B - 1) / B, B, 0, stream>>>(payD, dinv, E);
        k_bagg1o<<<NB, B, 0, stream>>>(bbD, payD, h1h, dinv, b1, acc1, n);
        k_layer2f<<<(n + B - 1) / B, B, 0, stream>>>(acc1, W2, h2f, n);
        k_bagg2o<<<NB, B, 0, stream>>>(bbD, payD, h2f, dinv, b2, out, n);
    }
}